// Round 1
// baseline (474.702 us; speedup 1.0000x reference)
//
#include <hip/hip_runtime.h>
#include <hip/hip_bf16.h>

#define B_ 4
#define S_ 2048
#define HID_ 1024
#define NH_ 16
#define HD_ 64
#define M_ (B_*S_)   // 8192

typedef __attribute__((ext_vector_type(8))) short short8;
typedef __attribute__((ext_vector_type(4))) float f32x4;
typedef __attribute__((ext_vector_type(4))) short short4v;

static __device__ __forceinline__ short bf16_of(float f){
    union { __hip_bfloat16 h; short s; } u;
    u.h = __float2bfloat16(f);
    return u.s;
}

// ---------------- cast hidden f32 -> bf16 ----------------
__global__ __launch_bounds__(256) void cast_x_kernel(const float* __restrict__ x,
                                                     short* __restrict__ xb, int n4){
    int i = blockIdx.x*blockDim.x + threadIdx.x;
    if (i >= n4) return;
    float4 f = reinterpret_cast<const float4*>(x)[i];
    short4v o;
    o.x = bf16_of(f.x); o.y = bf16_of(f.y); o.z = bf16_of(f.z); o.w = bf16_of(f.w);
    reinterpret_cast<short4v*>(xb)[i] = o;
}

// ------------- cast + transpose weight: Wt[n][k] = W[k][n], bf16 -------------
__global__ __launch_bounds__(256) void castT_w_kernel(const float* __restrict__ W,
                                                      short* __restrict__ Wt){
    __shared__ float tl[64][65];
    int k0 = blockIdx.x*64, n0 = blockIdx.y*64;
    int t = threadIdx.x;
    int r = t>>2, cg = (t&3)*16;
    #pragma unroll
    for (int j=0;j<4;j++){
        float4 f = *reinterpret_cast<const float4*>(&W[(k0+r)*HID_ + n0 + cg + j*4]);
        tl[r][cg+j*4+0]=f.x; tl[r][cg+j*4+1]=f.y; tl[r][cg+j*4+2]=f.z; tl[r][cg+j*4+3]=f.w;
    }
    __syncthreads();
    short8 o0, o1;
    #pragma unroll
    for (int j=0;j<8;j++) o0[j] = bf16_of(tl[cg+j][r]);
    #pragma unroll
    for (int j=0;j<8;j++) o1[j] = bf16_of(tl[cg+8+j][r]);
    *reinterpret_cast<short8*>(&Wt[(n0+r)*HID_ + k0 + cg])     = o0;
    *reinterpret_cast<short8*>(&Wt[(n0+r)*HID_ + k0 + cg + 8]) = o1;
}

// ------------- GEMM: C[m][n] = A[m][:] . Wt[n][:] + bias[n] -------------
// A: [M_,1024] bf16 row-major; Wt: [1024,1024] bf16 (pre-transposed: row n holds W[:,n])
// OMODE 0: write bf16 to headed layout [b, h, s, d]
// OMODE 1: write f32 to flat [m][n]
template<int OMODE>
__global__ __launch_bounds__(256) void gemm_bt(const short* __restrict__ A,
        const short* __restrict__ Wt, const float* __restrict__ bias,
        void* __restrict__ outp){
    __shared__ short As[128*40];
    __shared__ short Bs[128*40];
    int tid = threadIdx.x;
    int lane = tid & 63, wid = tid >> 6;
    int wm = wid >> 1, wn = wid & 1;
    int lr = lane & 15, lg = lane >> 4;
    int m0 = blockIdx.x * 128;
    int n0 = blockIdx.y * 128;
    f32x4 acc[4][4] = {};
    for (int kk = 0; kk < 1024; kk += 32){
        #pragma unroll
        for (int i=0;i<2;i++){
            int row = (tid>>2) + i*64;
            int c8 = (tid&3)*8;
            *reinterpret_cast<short8*>(&As[row*40 + c8]) =
                *reinterpret_cast<const short8*>(&A[(m0+row)*1024 + kk + c8]);
            *reinterpret_cast<short8*>(&Bs[row*40 + c8]) =
                *reinterpret_cast<const short8*>(&Wt[(n0+row)*1024 + kk + c8]);
        }
        __syncthreads();
        short8 af[4], bfr[4];
        #pragma unroll
        for (int x=0;x<4;x++){
            af[x]  = *reinterpret_cast<const short8*>(&As[(wm*64 + x*16 + lr)*40 + lg*8]);
            bfr[x] = *reinterpret_cast<const short8*>(&Bs[(wn*64 + x*16 + lr)*40 + lg*8]);
        }
        #pragma unroll
        for (int mi=0;mi<4;mi++)
            #pragma unroll
            for (int ni=0;ni<4;ni++)
                acc[mi][ni] = __builtin_amdgcn_mfma_f32_16x16x32_bf16(af[mi], bfr[ni], acc[mi][ni], 0,0,0);
        __syncthreads();
    }
    #pragma unroll
    for (int mi=0;mi<4;mi++){
      #pragma unroll
      for (int ni=0;ni<4;ni++){
        int colg = n0 + wn*64 + ni*16 + lr;
        float bv = bias[colg];
        #pragma unroll
        for (int r=0;r<4;r++){
            int rowg = m0 + wm*64 + mi*16 + lg*4 + r;
            float v = acc[mi][ni][r] + bv;
            if (OMODE == 0){
                int bidx = rowg >> 11, s = rowg & 2047;
                int h = colg >> 6, d = colg & 63;
                reinterpret_cast<short*>(outp)[(((bidx*NH_ + h)*S_) + s)*HD_ + d] = bf16_of(v);
            } else {
                reinterpret_cast<float*>(outp)[rowg*1024 + colg] = v;
            }
        }
      }
    }
}

// ------------- transpose V: [b,h,s,d] -> [b,h,d,s] (bf16) -------------
__global__ __launch_bounds__(256) void transpose_v(const short* __restrict__ vb,
                                                   short* __restrict__ vt){
    __shared__ short tl[64*72];
    int bh = blockIdx.z*NH_ + blockIdx.y;
    int s0 = blockIdx.x*64;
    int t = threadIdx.x;
    int c8 = (t&7)*8;
    #pragma unroll
    for (int i=0;i<2;i++){
        int row = (t>>3) + i*32;
        *reinterpret_cast<short8*>(&tl[row*72 + c8]) =
            *reinterpret_cast<const short8*>(&vb[(bh*S_ + s0 + row)*HD_ + c8]);
    }
    __syncthreads();
    #pragma unroll
    for (int i=0;i<2;i++){
        int d = (t>>3) + i*32;
        short8 o;
        #pragma unroll
        for (int j=0;j<8;j++) o[j] = tl[(c8+j)*72 + d];
        *reinterpret_cast<short8*>(&vt[(bh*HD_ + d)*S_ + s0 + c8]) = o;
    }
}

// ------------- fused attention: per (b, h, 64 q-rows) -------------
__global__ __launch_bounds__(256) void attn_kernel(const short* __restrict__ qb,
    const short* __restrict__ kbuf, const short* __restrict__ vtg,
    const float* __restrict__ med_mask, const float* __restrict__ att_mask,
    const float* __restrict__ rel, short* __restrict__ ctxg){
    __shared__ short Ks[64*72];
    __shared__ short Vt[64*72];
    __shared__ short Ps[4][16*72];
    int t = threadIdx.x;
    int lane = t & 63, wid = t >> 6;
    int lr = lane & 15, lg = lane >> 4;
    int h = blockIdx.y, b = blockIdx.z;
    int bh = b*NH_ + h;
    int q0 = blockIdx.x*64 + wid*16;   // this wave's 16 q rows start here

    short8 qf[2];
    #pragma unroll
    for (int tt=0;tt<2;tt++)
        qf[tt] = *reinterpret_cast<const short8*>(&qb[(bh*S_ + q0 + lr)*HD_ + tt*32 + lg*8]);

    float mq[4];
    #pragma unroll
    for (int r=0;r<4;r++) mq[r] = med_mask[b*S_ + q0 + lg*4 + r];

    float m_run[4], l_run[4];
    f32x4 ctx[4] = {};
    #pragma unroll
    for (int r=0;r<4;r++){ m_run[r] = -1e30f; l_run[r] = 0.f; }

    int c8 = (t&7)*8;
    for (int kt = 0; kt < S_/64; kt++){
        int kb0 = kt*64;
        #pragma unroll
        for (int i=0;i<2;i++){
            int row = (t>>3) + i*32;
            *reinterpret_cast<short8*>(&Ks[row*72 + c8]) =
                *reinterpret_cast<const short8*>(&kbuf[(bh*S_ + kb0 + row)*HD_ + c8]);
            *reinterpret_cast<short8*>(&Vt[row*72 + c8]) =
                *reinterpret_cast<const short8*>(&vtg[(bh*HD_ + row)*S_ + kb0 + c8]);
        }
        __syncthreads();

        // scores S[q=lg*4+r][kc=c*16+lr] for this wave's 16 q rows x 64 k cols
        f32x4 sa[4] = {};
        #pragma unroll
        for (int c=0;c<4;c++){
            #pragma unroll
            for (int tt=0;tt<2;tt++){
                short8 kf = *reinterpret_cast<const short8*>(&Ks[(c*16+lr)*72 + tt*32 + lg*8]);
                sa[c] = __builtin_amdgcn_mfma_f32_16x16x32_bf16(qf[tt], kf, sa[c], 0,0,0);
            }
        }
        // scale + medical bias + attention mask
        #pragma unroll
        for (int c=0;c<4;c++){
            int col = kb0 + c*16 + lr;
            float km = med_mask[b*S_ + col];
            float am = att_mask[b*S_ + col];
            float addm = (1.f - am)*(-10000.f);
            #pragma unroll
            for (int r=0;r<4;r++){
                float sv = sa[c][r]*0.125f;
                if (mq[r] != 0.f)   // group-uniform across the 16 lanes of a row set
                    sv += mq[r]*km*0.1f*rel[(q0 + lg*4 + r)*2048 + col];
                sv += addm;
                sa[c][r] = sv;
            }
        }
        // online softmax (row reduce across lr = lanes 0..15 of each group)
        #pragma unroll
        for (int r=0;r<4;r++){
            float vm = fmaxf(fmaxf(sa[0][r], sa[1][r]), fmaxf(sa[2][r], sa[3][r]));
            #pragma unroll
            for (int off=1;off<16;off<<=1) vm = fmaxf(vm, __shfl_xor(vm, off));
            float mn = fmaxf(m_run[r], vm);
            float ef = __expf(m_run[r] - mn);
            m_run[r] = mn;
            float ps = 0.f;
            #pragma unroll
            for (int c=0;c<4;c++){
                float p = __expf(sa[c][r] - mn);
                sa[c][r] = p;
                ps += p;
            }
            #pragma unroll
            for (int off=1;off<16;off<<=1) ps += __shfl_xor(ps, off);
            l_run[r] = l_run[r]*ef + ps;
            #pragma unroll
            for (int c=0;c<4;c++) ctx[c][r] *= ef;
        }
        // P -> LDS (per-wave region), then read back as MFMA A fragments
        #pragma unroll
        for (int c=0;c<4;c++)
            #pragma unroll
            for (int r=0;r<4;r++)
                Ps[wid][(lg*4+r)*72 + c*16 + lr] = bf16_of(sa[c][r]);
        __syncthreads();
        short8 pf[2];
        #pragma unroll
        for (int tt=0;tt<2;tt++)
            pf[tt] = *reinterpret_cast<const short8*>(&Ps[wid][lr*72 + tt*32 + lg*8]);
        #pragma unroll
        for (int c2=0;c2<4;c2++){
            #pragma unroll
            for (int tt=0;tt<2;tt++){
                short8 vf = *reinterpret_cast<const short8*>(&Vt[(c2*16+lr)*72 + tt*32 + lg*8]);
                ctx[c2] = __builtin_amdgcn_mfma_f32_16x16x32_bf16(pf[tt], vf, ctx[c2], 0,0,0);
            }
        }
        __syncthreads();
    }
    #pragma unroll
    for (int c2=0;c2<4;c2++){
        #pragma unroll
        for (int r=0;r<4;r++){
            int row = q0 + lg*4 + r;
            float v = ctx[c2][r] / l_run[r];
            ctxg[(b*S_ + row)*HID_ + h*HD_ + c2*16 + lr] = bf16_of(v);
        }
    }
}

// ------------- residual + LayerNorm -------------
__global__ __launch_bounds__(256) void ln_kernel(const float* __restrict__ og,
    const float* __restrict__ hidden, const float* __restrict__ g,
    const float* __restrict__ bb, float* __restrict__ out){
    int row = blockIdx.x;
    int t = threadIdx.x;
    float4 o  = *reinterpret_cast<const float4*>(&og[row*HID_ + t*4]);
    float4 hv = *reinterpret_cast<const float4*>(&hidden[row*HID_ + t*4]);
    float x0 = o.x + hv.x, x1 = o.y + hv.y, x2 = o.z + hv.z, x3 = o.w + hv.w;
    float s = x0+x1+x2+x3;
    float q = x0*x0+x1*x1+x2*x2+x3*x3;
    #pragma unroll
    for (int off=1;off<64;off<<=1){ s += __shfl_xor(s,off); q += __shfl_xor(q,off); }
    __shared__ float rs[4], rq[4];
    int lane = t&63, wid = t>>6;
    if (lane==0){ rs[wid]=s; rq[wid]=q; }
    __syncthreads();
    s = rs[0]+rs[1]+rs[2]+rs[3];
    q = rq[0]+rq[1]+rq[2]+rq[3];
    float mu  = s * (1.f/1024.f);
    float var = q * (1.f/1024.f) - mu*mu;
    float inv = rsqrtf(var + 1e-12f);
    float4 gv = *reinterpret_cast<const float4*>(&g[t*4]);
    float4 bv = *reinterpret_cast<const float4*>(&bb[t*4]);
    float4 y;
    y.x = (x0-mu)*inv*gv.x + bv.x;
    y.y = (x1-mu)*inv*gv.y + bv.y;
    y.z = (x2-mu)*inv*gv.z + bv.z;
    y.w = (x3-mu)*inv*gv.w + bv.w;
    *reinterpret_cast<float4*>(&out[row*HID_ + t*4]) = y;
}

extern "C" void kernel_launch(void* const* d_in, const int* in_sizes, int n_in,
                              void* d_out, int out_size, void* d_ws, size_t ws_size,
                              hipStream_t stream){
    const float* hidden = (const float*)d_in[0];
    const float* amask  = (const float*)d_in[1];
    const float* mmask  = (const float*)d_in[2];
    const float* Wq = (const float*)d_in[3];
    const float* bq = (const float*)d_in[4];
    const float* Wk = (const float*)d_in[5];
    const float* bk = (const float*)d_in[6];
    const float* Wv = (const float*)d_in[7];
    const float* bv = (const float*)d_in[8];
    const float* rel = (const float*)d_in[9];
    const float* Wd = (const float*)d_in[10];
    const float* bd = (const float*)d_in[11];
    const float* lng = (const float*)d_in[12];
    const float* lnb = (const float*)d_in[13];
    float* out = (float*)d_out;

    char* ws = (char*)d_ws;
    short* xb  = (short*)(ws);                       // 16MB  bf16 hidden
    short* wt  = (short*)(ws + (16u<<20));           // 8MB   4x bf16 W^T
    short* qb  = (short*)(ws + (24u<<20));           // 16MB  q [b,h,s,d]
    short* kb2 = (short*)(ws + (40u<<20));           // 16MB  k [b,h,s,d]
    short* vb  = (short*)(ws + (56u<<20));           // 16MB  v [b,h,s,d]
    short* vtb = (short*)(ws + (72u<<20));           // 16MB  v [b,h,d,s]
    short* ctx = (short*)(ws + (88u<<20));           // 16MB  ctx [b,s,hid]
    float* og  = (float*)(ws + (24u<<20));           // 32MB  aliases qb+kb (dead after attn)

    cast_x_kernel<<<8192, 256, 0, stream>>>(hidden, xb, M_*HID_/4);
    dim3 gw(16,16);
    castT_w_kernel<<<gw, 256, 0, stream>>>(Wq, wt + 0*(1u<<20));
    castT_w_kernel<<<gw, 256, 0, stream>>>(Wk, wt + 1*(1u<<20));
    castT_w_kernel<<<gw, 256, 0, stream>>>(Wv, wt + 2*(1u<<20));
    castT_w_kernel<<<gw, 256, 0, stream>>>(Wd, wt + 3*(1u<<20));
    dim3 gg(64, 8);
    gemm_bt<0><<<gg, 256, 0, stream>>>(xb, wt + 0*(1u<<20), bq, qb);
    gemm_bt<0><<<gg, 256, 0, stream>>>(xb, wt + 1*(1u<<20), bk, kb2);
    gemm_bt<0><<<gg, 256, 0, stream>>>(xb, wt + 2*(1u<<20), bv, vb);
    transpose_v<<<dim3(32,NH_,B_), 256, 0, stream>>>(vb, vtb);
    attn_kernel<<<dim3(32,NH_,B_), 256, 0, stream>>>(qb, kb2, vtb, mmask, amask, rel, ctx);
    gemm_bt<1><<<gg, 256, 0, stream>>>(ctx, wt + 3*(1u<<20), bd, og);
    ln_kernel<<<8192, 256, 0, stream>>>(og, hidden, lng, lnb, out);
}

// Round 2
// 368.907 us; speedup vs baseline: 1.2868x; 1.2868x over previous
//
#include <hip/hip_runtime.h>
#include <hip/hip_bf16.h>

#define B_ 4
#define S_ 2048
#define HID_ 1024
#define NH_ 16
#define HD_ 64
#define M_ (B_*S_)   // 8192

typedef __attribute__((ext_vector_type(8))) short short8;
typedef __attribute__((ext_vector_type(4))) float f32x4;
typedef __attribute__((ext_vector_type(16))) float f32x16;
typedef __attribute__((ext_vector_type(4))) short short4v;
typedef __attribute__((ext_vector_type(2))) int int2v;
typedef __attribute__((ext_vector_type(4))) int int4v;

static __device__ __forceinline__ short bf16_of(float f){
    union { __hip_bfloat16 h; short s; } u;
    u.h = __float2bfloat16(f);
    return u.s;
}

static __device__ __forceinline__ int cvtpk_bf16(float lo, float hi){
    int r;
    asm("v_cvt_pk_bf16_f32 %0, %1, %2" : "=v"(r) : "v"(lo), "v"(hi));
    return r;
}

// partner value across the lane<32 / lane>=32 halves
static __device__ __forceinline__ float half_other(float v, bool lo){
    int2v r = __builtin_amdgcn_permlane32_swap(__float_as_int(v), __float_as_int(v), false, false);
    return __int_as_float(lo ? r.y : r.x);
}

// ---------------- cast hidden f32 -> bf16 ----------------
__global__ __launch_bounds__(256) void cast_x_kernel(const float* __restrict__ x,
                                                     short* __restrict__ xb, int n4){
    int i = blockIdx.x*blockDim.x + threadIdx.x;
    if (i >= n4) return;
    float4 f = reinterpret_cast<const float4*>(x)[i];
    short4v o;
    o.x = bf16_of(f.x); o.y = bf16_of(f.y); o.z = bf16_of(f.z); o.w = bf16_of(f.w);
    reinterpret_cast<short4v*>(xb)[i] = o;
}

// ------------- cast + transpose weight: Wt[n][k] = W[k][n], bf16 -------------
__global__ __launch_bounds__(256) void castT_w_kernel(const float* __restrict__ W,
                                                      short* __restrict__ Wt){
    __shared__ float tl[64][65];
    int k0 = blockIdx.x*64, n0 = blockIdx.y*64;
    int t = threadIdx.x;
    int r = t>>2, cg = (t&3)*16;
    #pragma unroll
    for (int j=0;j<4;j++){
        float4 f = *reinterpret_cast<const float4*>(&W[(k0+r)*HID_ + n0 + cg + j*4]);
        tl[r][cg+j*4+0]=f.x; tl[r][cg+j*4+1]=f.y; tl[r][cg+j*4+2]=f.z; tl[r][cg+j*4+3]=f.w;
    }
    __syncthreads();
    short8 o0, o1;
    #pragma unroll
    for (int j=0;j<8;j++) o0[j] = bf16_of(tl[cg+j][r]);
    #pragma unroll
    for (int j=0;j<8;j++) o1[j] = bf16_of(tl[cg+8+j][r]);
    *reinterpret_cast<short8*>(&Wt[(n0+r)*HID_ + k0 + cg])     = o0;
    *reinterpret_cast<short8*>(&Wt[(n0+r)*HID_ + k0 + cg + 8]) = o1;
}

// ------------- GEMM: C[m][n] = A[m][:] . Wt[n][:] + bias[n] -------------
template<int OMODE>
__global__ __launch_bounds__(256) void gemm_bt(const short* __restrict__ A,
        const short* __restrict__ Wt, const float* __restrict__ bias,
        void* __restrict__ outp){
    __shared__ short As[128*40];
    __shared__ short Bs[128*40];
    int tid = threadIdx.x;
    int lane = tid & 63, wid = tid >> 6;
    int wm = wid >> 1, wn = wid & 1;
    int lr = lane & 15, lg = lane >> 4;
    int m0 = blockIdx.x * 128;
    int n0 = blockIdx.y * 128;
    f32x4 acc[4][4] = {};
    for (int kk = 0; kk < 1024; kk += 32){
        #pragma unroll
        for (int i=0;i<2;i++){
            int row = (tid>>2) + i*64;
            int c8 = (tid&3)*8;
            *reinterpret_cast<short8*>(&As[row*40 + c8]) =
                *reinterpret_cast<const short8*>(&A[(m0+row)*1024 + kk + c8]);
            *reinterpret_cast<short8*>(&Bs[row*40 + c8]) =
                *reinterpret_cast<const short8*>(&Wt[(n0+row)*1024 + kk + c8]);
        }
        __syncthreads();
        short8 af[4], bfr[4];
        #pragma unroll
        for (int x=0;x<4;x++){
            af[x]  = *reinterpret_cast<const short8*>(&As[(wm*64 + x*16 + lr)*40 + lg*8]);
            bfr[x] = *reinterpret_cast<const short8*>(&Bs[(wn*64 + x*16 + lr)*40 + lg*8]);
        }
        #pragma unroll
        for (int mi=0;mi<4;mi++)
            #pragma unroll
            for (int ni=0;ni<4;ni++)
                acc[mi][ni] = __builtin_amdgcn_mfma_f32_16x16x32_bf16(af[mi], bfr[ni], acc[mi][ni], 0,0,0);
        __syncthreads();
    }
    #pragma unroll
    for (int mi=0;mi<4;mi++){
      #pragma unroll
      for (int ni=0;ni<4;ni++){
        int colg = n0 + wn*64 + ni*16 + lr;
        float bv = bias[colg];
        #pragma unroll
        for (int r=0;r<4;r++){
            int rowg = m0 + wm*64 + mi*16 + lg*4 + r;
            float v = acc[mi][ni][r] + bv;
            if (OMODE == 0){
                int bidx = rowg >> 11, s = rowg & 2047;
                int hh = colg >> 6, d = colg & 63;
                reinterpret_cast<short*>(outp)[(((bidx*NH_ + hh)*S_) + s)*HD_ + d] = bf16_of(v);
            } else {
                reinterpret_cast<float*>(outp)[rowg*1024 + colg] = v;
            }
        }
      }
    }
}

// ------------- transpose V: [b,h,s,d] -> [b,h,d,s] (bf16) -------------
__global__ __launch_bounds__(256) void transpose_v(const short* __restrict__ vb,
                                                   short* __restrict__ vt){
    __shared__ short tl[64*72];
    int bh = blockIdx.z*NH_ + blockIdx.y;
    int s0 = blockIdx.x*64;
    int t = threadIdx.x;
    int c8 = (t&7)*8;
    #pragma unroll
    for (int i=0;i<2;i++){
        int row = (t>>3) + i*32;
        *reinterpret_cast<short8*>(&tl[row*72 + c8]) =
            *reinterpret_cast<const short8*>(&vb[(bh*S_ + s0 + row)*HD_ + c8]);
    }
    __syncthreads();
    #pragma unroll
    for (int i=0;i<2;i++){
        int d = (t>>3) + i*32;
        short8 o;
        #pragma unroll
        for (int j=0;j<8;j++) o[j] = tl[(c8+j)*72 + d];
        *reinterpret_cast<short8*>(&vt[(bh*HD_ + d)*S_ + s0 + c8]) = o;
    }
}

// ------------- bias precompute: bias2[b][col] = {mk*0.1*log2e, (1-am)*(-1e4)*log2e} -------------
__global__ __launch_bounds__(256) void prep_bias(const float* __restrict__ mm_,
        const float* __restrict__ am_, float* __restrict__ bias2){
    int i = blockIdx.x*256 + threadIdx.x;
    if (i >= B_*S_) return;
    bias2[2*i]   = mm_[i] * (0.1f * 1.44269504f);
    bias2[2*i+1] = (1.f - am_[i]) * (-10000.f * 1.44269504f);
}

// ------------- fused attention v2: 4 warps x 32 q-rows, 32x32x16 MFMA, swapped ops -------------
__global__ __launch_bounds__(256, 3) void attn2_kernel(
    const short* __restrict__ qb, const short* __restrict__ kbuf,
    const short* __restrict__ vtg, const float* __restrict__ med_mask,
    const float* __restrict__ bias2, const float* __restrict__ rel,
    short* __restrict__ ctxg)
{
    __shared__ alignas(16) char smem[32768];   // K dbuf [2][64][64], V dbuf [2][64][64]
    const int t = threadIdx.x;
    const int lane = t & 63, wid = t >> 6;
    const int hi = lane >> 5, lr = lane & 31, lr7 = lr & 7;
    const bool lo = (hi == 0);
    const int h = blockIdx.y, b = blockIdx.z;
    const int bh = b*NH_ + h;
    const int q = blockIdx.x*128 + wid*32 + lr;

    // Q fragments (B-operand): qf[mm] = Q[q][mm*16 + hi*8 + jj]
    short8 qf[4];
    #pragma unroll
    for (int mm=0;mm<4;mm++)
        qf[mm] = *reinterpret_cast<const short8*>(&qb[((size_t)bh*S_ + q)*HD_ + mm*16 + hi*8]);

    const float mqs = med_mask[b*S_ + q];
    const float CQ = 0.18033688f;   // 0.125 * log2(e)

    float m_run = -3e38f, l_run = 0.f;
    f32x16 oa0 = {}, oa1 = {};

    const short* kg_base = kbuf + (size_t)bh*S_*HD_;
    const short* vg_base = vtg  + (size_t)bh*HD_*S_;
    const float* b2 = bias2 + (size_t)b*S_*2;
    const float* relrow = rel + (size_t)q*2048;

    // staging geometry: 512 chunks of 16B per 8KB tile, 2 per thread
    const int i0 = t, i1 = t + 256;
    const int wby0 = (i0<<4) ^ (((i0>>3)&7)<<4);
    const int wby1 = (i1<<4) ^ (((i1>>3)&7)<<4);
    const size_t koff0 = (size_t)i0*8, koff1 = (size_t)i1*8;
    const size_t voff0 = (size_t)(i0>>3)*S_ + (size_t)(i0&7)*8;
    const size_t voff1 = (size_t)(i1>>3)*S_ + (size_t)(i1&7)*8;

    // prologue: stage tile 0 into buffer 0
    {
        short8 a = *(const short8*)(kg_base + koff0);
        short8 c = *(const short8*)(kg_base + koff1);
        short8 d = *(const short8*)(vg_base + voff0);
        short8 e = *(const short8*)(vg_base + voff1);
        *(short8*)(smem + wby0) = a;
        *(short8*)(smem + wby1) = c;
        *(short8*)(smem + 16384 + wby0) = d;
        *(short8*)(smem + 16384 + wby1) = e;
    }
    __syncthreads();

    int cur = 0;
    const int NT = S_/64;
    for (int tt = 0; tt < NT; ++tt){
        const int kb0 = tt*64;
        // issue next-tile loads early (hide HBM under compute)
        short8 ng0, ng1, ng2, ng3;
        if (tt < NT-1){
            const short* kg = kg_base + (size_t)(kb0+64)*HD_;
            const short* vg = vg_base + (kb0+64);
            ng0 = *(const short8*)(kg + koff0);
            ng1 = *(const short8*)(kg + koff1);
            ng2 = *(const short8*)(vg + voff0);
            ng3 = *(const short8*)(vg + voff1);
        }
        char* kb_lds = smem + cur*8192;
        char* vb_lds = smem + 16384 + cur*8192;

        // ---- QK^T (swapped): p[sub] = S[q][kb0+sub*32+crow(r,hi)] ----
        f32x16 p0 = {}, p1 = {};
        __builtin_amdgcn_s_setprio(1);
        #pragma unroll
        for (int mm=0;mm<4;mm++){
            int swz = ((2*mm+hi) ^ lr7) << 4;
            short8 kf0 = *(const short8*)(kb_lds + lr*128 + swz);
            short8 kf1 = *(const short8*)(kb_lds + (32+lr)*128 + swz);
            p0 = __builtin_amdgcn_mfma_f32_32x32x16_bf16(kf0, qf[mm], p0, 0,0,0);
            p1 = __builtin_amdgcn_mfma_f32_32x32x16_bf16(kf1, qf[mm], p1, 0,0,0);
        }
        __builtin_amdgcn_s_setprio(0);

        // ---- scale + mask bias (log2e units) ----
        const float* b2t = b2 + (size_t)kb0*2;
        #pragma unroll
        for (int sub=0; sub<2; sub++){
            #pragma unroll
            for (int g=0; g<4; g++){
                const int cb = sub*32 + 8*g + 4*hi;
                float4 bA = *(const float4*)(b2t + cb*2);
                float4 bB = *(const float4*)(b2t + cb*2 + 4);
                f32x16& P = (sub==0) ? p0 : p1;
                P[4*g+0] = fmaf(P[4*g+0], CQ, bA.y);
                P[4*g+1] = fmaf(P[4*g+1], CQ, bA.w);
                P[4*g+2] = fmaf(P[4*g+2], CQ, bB.y);
                P[4*g+3] = fmaf(P[4*g+3], CQ, bB.w);
            }
        }
        // medical term: only ~20% of q rows active (lane-uniform predicate)
        if (mqs != 0.f){
            const float* rr = relrow + kb0;
            #pragma unroll
            for (int sub=0; sub<2; sub++){
                #pragma unroll
                for (int g=0; g<4; g++){
                    const int cb = sub*32 + 8*g + 4*hi;
                    float4 rv = *(const float4*)(rr + cb);
                    float4 bA = *(const float4*)(b2t + cb*2);
                    float4 bB = *(const float4*)(b2t + cb*2 + 4);
                    f32x16& P = (sub==0) ? p0 : p1;
                    P[4*g+0] += mqs * bA.x * rv.x;
                    P[4*g+1] += mqs * bA.z * rv.y;
                    P[4*g+2] += mqs * bB.x * rv.z;
                    P[4*g+3] += mqs * bB.z * rv.w;
                }
            }
        }

        // ---- online softmax: row is lane-local + one half-swap ----
        float q0m = fmaxf(fmaxf(p0[0],p0[1]),  fmaxf(p0[2],p0[3]));
        float q1m = fmaxf(fmaxf(p0[4],p0[5]),  fmaxf(p0[6],p0[7]));
        float q2m = fmaxf(fmaxf(p0[8],p0[9]),  fmaxf(p0[10],p0[11]));
        float q3m = fmaxf(fmaxf(p0[12],p0[13]),fmaxf(p0[14],p0[15]));
        float q4m = fmaxf(fmaxf(p1[0],p1[1]),  fmaxf(p1[2],p1[3]));
        float q5m = fmaxf(fmaxf(p1[4],p1[5]),  fmaxf(p1[6],p1[7]));
        float q6m = fmaxf(fmaxf(p1[8],p1[9]),  fmaxf(p1[10],p1[11]));
        float q7m = fmaxf(fmaxf(p1[12],p1[13]),fmaxf(p1[14],p1[15]));
        float mt = fmaxf(fmaxf(fmaxf(q0m,q1m),fmaxf(q2m,q3m)),
                         fmaxf(fmaxf(q4m,q5m),fmaxf(q6m,q7m)));
        mt = fmaxf(mt, half_other(mt, lo));
        float mnew = fmaxf(m_run, mt);
        float ef = exp2f(m_run - mnew);
        m_run = mnew;

        #pragma unroll
        for (int r=0;r<16;r++) p0[r] = exp2f(p0[r]-mnew);
        #pragma unroll
        for (int r=0;r<16;r++) p1[r] = exp2f(p1[r]-mnew);

        float s00 = (p0[0]+p0[1])+(p0[2]+p0[3]);
        float s01 = (p0[4]+p0[5])+(p0[6]+p0[7]);
        float s02 = (p0[8]+p0[9])+(p0[10]+p0[11]);
        float s03 = (p0[12]+p0[13])+(p0[14]+p0[15]);
        float s10 = (p1[0]+p1[1])+(p1[2]+p1[3]);
        float s11 = (p1[4]+p1[5])+(p1[6]+p1[7]);
        float s12 = (p1[8]+p1[9])+(p1[10]+p1[11]);
        float s13 = (p1[12]+p1[13])+(p1[14]+p1[15]);
        float rs = ((s00+s01)+(s02+s03)) + ((s10+s11)+(s12+s13));
        rs += half_other(rs, lo);
        l_run = l_run*ef + rs;

        #pragma unroll
        for (int r=0;r<16;r++){ oa0[r]*=ef; oa1[r]*=ef; }

        // ---- P -> bf16 B-fragments via cvt_pk + permlane32_swap ----
        short8 pf[4];
        #pragma unroll
        for (int kb=0;kb<4;kb++){
            const f32x16& P = (kb<2) ? p0 : p1;
            const int r0 = 8*(kb&1);
            int X0 = cvtpk_bf16(P[r0+0], P[r0+1]);
            int Y0 = cvtpk_bf16(P[r0+2], P[r0+3]);
            int X1 = cvtpk_bf16(P[r0+4], P[r0+5]);
            int Y1 = cvtpk_bf16(P[r0+6], P[r0+7]);
            int2v w02 = __builtin_amdgcn_permlane32_swap(X0, X1, false, false);
            int2v w13 = __builtin_amdgcn_permlane32_swap(Y0, Y1, false, false);
            pf[kb] = __builtin_bit_cast(short8, (int4v){w02.x, w13.x, w02.y, w13.y});
        }

        // ---- PV (swapped): oa[db] += mfma(Vt_frag, P_frag) ----
        __builtin_amdgcn_s_setprio(1);
        #pragma unroll
        for (int kb=0;kb<4;kb++){
            int swz = ((2*kb+hi) ^ lr7) << 4;
            short8 vf0 = *(const short8*)(vb_lds + lr*128 + swz);
            short8 vf1 = *(const short8*)(vb_lds + (32+lr)*128 + swz);
            oa0 = __builtin_amdgcn_mfma_f32_32x32x16_bf16(vf0, pf[kb], oa0, 0,0,0);
            oa1 = __builtin_amdgcn_mfma_f32_32x32x16_bf16(vf1, pf[kb], oa1, 0,0,0);
        }
        __builtin_amdgcn_s_setprio(0);

        // ---- write next tile into the other buffer ----
        if (tt < NT-1){
            char* kd = smem + (cur^1)*8192;
            char* vd = smem + 16384 + (cur^1)*8192;
            *(short8*)(kd + wby0) = ng0;
            *(short8*)(kd + wby1) = ng1;
            *(short8*)(vd + wby0) = ng2;
            *(short8*)(vd + wby1) = ng3;
        }
        __syncthreads();
        cur ^= 1;
    }

    // ---- epilogue: O/l -> bf16, LDS transpose stage, coalesced store ----
    char* ost = smem + wid*4096;
    float invl = 1.f / l_run;
    #pragma unroll
    for (int db=0; db<2; db++){
        const f32x16& O = (db==0) ? oa0 : oa1;
        #pragma unroll
        for (int g=0; g<4; g++){
            int w0 = cvtpk_bf16(O[4*g+0]*invl, O[4*g+1]*invl);
            int w1 = cvtpk_bf16(O[4*g+2]*invl, O[4*g+3]*invl);
            int by = lr*128 + (((4*db+g) ^ lr7)<<4) + hi*8;
            *reinterpret_cast<int2v*>(ost + by) = (int2v){w0, w1};
        }
    }
    __syncthreads();
    const size_t obase = ((size_t)b*S_ + blockIdx.x*128 + wid*32)*HID_ + h*HD_;
    #pragma unroll
    for (int i=0;i<4;i++){
        int row = i*8 + (lane>>3);
        int c = lane&7;
        short8 v = *(const short8*)(ost + row*128 + ((c ^ (row&7))<<4));
        *reinterpret_cast<short8*>(&ctxg[obase + (size_t)row*HID_ + c*8]) = v;
    }
}

// ------------- residual + LayerNorm -------------
__global__ __launch_bounds__(256) void ln_kernel(const float* __restrict__ og,
    const float* __restrict__ hidden, const float* __restrict__ g,
    const float* __restrict__ bb, float* __restrict__ out){
    int row = blockIdx.x;
    int t = threadIdx.x;
    float4 o  = *reinterpret_cast<const float4*>(&og[row*HID_ + t*4]);
    float4 hv = *reinterpret_cast<const float4*>(&hidden[row*HID_ + t*4]);
    float x0 = o.x + hv.x, x1 = o.y + hv.y, x2 = o.z + hv.z, x3 = o.w + hv.w;
    float s = x0+x1+x2+x3;
    float qq = x0*x0+x1*x1+x2*x2+x3*x3;
    #pragma unroll
    for (int off=1;off<64;off<<=1){ s += __shfl_xor(s,off); qq += __shfl_xor(qq,off); }
    __shared__ float rs[4], rq[4];
    int lane = t&63, wid = t>>6;
    if (lane==0){ rs[wid]=s; rq[wid]=qq; }
    __syncthreads();
    s = rs[0]+rs[1]+rs[2]+rs[3];
    qq = rq[0]+rq[1]+rq[2]+rq[3];
    float mu  = s * (1.f/1024.f);
    float var = qq * (1.f/1024.f) - mu*mu;
    float inv = rsqrtf(var + 1e-12f);
    float4 gv = *reinterpret_cast<const float4*>(&g[t*4]);
    float4 bv = *reinterpret_cast<const float4*>(&bb[t*4]);
    float4 y;
    y.x = (x0-mu)*inv*gv.x + bv.x;
    y.y = (x1-mu)*inv*gv.y + bv.y;
    y.z = (x2-mu)*inv*gv.z + bv.z;
    y.w = (x3-mu)*inv*gv.w + bv.w;
    *reinterpret_cast<float4*>(&out[row*HID_ + t*4]) = y;
}

extern "C" void kernel_launch(void* const* d_in, const int* in_sizes, int n_in,
                              void* d_out, int out_size, void* d_ws, size_t ws_size,
                              hipStream_t stream){
    const float* hidden = (const float*)d_in[0];
    const float* amask  = (const float*)d_in[1];
    const float* mmask  = (const float*)d_in[2];
    const float* Wq = (const float*)d_in[3];
    const float* bq = (const float*)d_in[4];
    const float* Wk = (const float*)d_in[5];
    const float* bk = (const float*)d_in[6];
    const float* Wv = (const float*)d_in[7];
    const float* bv = (const float*)d_in[8];
    const float* rel = (const float*)d_in[9];
    const float* Wd = (const float*)d_in[10];
    const float* bd = (const float*)d_in[11];
    const float* lng = (const float*)d_in[12];
    const float* lnb = (const float*)d_in[13];
    float* out = (float*)d_out;

    char* ws = (char*)d_ws;
    short* xb  = (short*)(ws);                       // 16MB  bf16 hidden (dead after QKV gemms)
    short* wt  = (short*)(ws + (16u<<20));           // 8MB   4x bf16 W^T
    short* qb  = (short*)(ws + (24u<<20));           // 16MB  q [b,h,s,d]
    short* kb2 = (short*)(ws + (40u<<20));           // 16MB  k [b,h,s,d]
    short* vb  = (short*)(ws + (56u<<20));           // 16MB  v [b,h,s,d]
    short* vtb = (short*)(ws + (72u<<20));           // 16MB  v [b,h,d,s]
    short* ctx = (short*)(ws + (88u<<20));           // 16MB  ctx [b,s,hid]
    float* og  = (float*)(ws + (24u<<20));           // 32MB  aliases qb+kb (dead after attn)
    float* bias2 = (float*)(ws);                     // 64KB  aliases xb (dead after QKV gemms)

    cast_x_kernel<<<8192, 256, 0, stream>>>(hidden, xb, M_*HID_/4);
    dim3 gw(16,16);
    castT_w_kernel<<<gw, 256, 0, stream>>>(Wq, wt + 0*(1u<<20));
    castT_w_kernel<<<gw, 256, 0, stream>>>(Wk, wt + 1*(1u<<20));
    castT_w_kernel<<<gw, 256, 0, stream>>>(Wv, wt + 2*(1u<<20));
    castT_w_kernel<<<gw, 256, 0, stream>>>(Wd, wt + 3*(1u<<20));
    dim3 gg(64, 8);
    gemm_bt<0><<<gg, 256, 0, stream>>>(xb, wt + 0*(1u<<20), bq, qb);
    gemm_bt<0><<<gg, 256, 0, stream>>>(xb, wt + 1*(1u<<20), bk, kb2);
    gemm_bt<0><<<gg, 256, 0, stream>>>(xb, wt + 2*(1u<<20), bv, vb);
    prep_bias<<<32, 256, 0, stream>>>(mmask, amask, bias2);   // after xb's last use
    transpose_v<<<dim3(32,NH_,B_), 256, 0, stream>>>(vb, vtb);
    attn2_kernel<<<dim3(16,NH_,B_), 256, 0, stream>>>(qb, kb2, vtb, mmask, bias2, rel, ctx);
    gemm_bt<1><<<gg, 256, 0, stream>>>(ctx, wt + 3*(1u<<20), bd, og);
    ln_kernel<<<8192, 256, 0, stream>>>(og, hidden, lng, lnb, out);
}